// Round 3
// baseline (93.167 us; speedup 1.0000x reference)
//
#include <hip/hip_runtime.h>

// loss = sum over flows/channels of mean_{b,h,w} || (I - P_A) patch ||^2
// P_A projects onto affine functions of patch offsets (a, c); the coordinate
// grids added in the reference are affine in (a,c) -> annihilated, so we can
// work on the raw flow channels.
// Residual via orthonormal basis: r = sumsq - sum^2/kz^2 - (sa^2 + sc^2)/S,
//   sa = sum (a-m) p, sc = sum (c-m) p, m = (kz-1)/2, S = kz * sum_t (t-m)^2.
//
// v4: occupancy-first. VX=2 everywhere (rolling stats = 3*KZ*2 = 30 VGPR for
//   kz=5), __launch_bounds__(256,6) to guarantee >=6 waves/SIMD (latency
//   hiding was the round-2 bottleneck theory: 3-5 waves/SIMD at ~900cy HBM
//   latency). STRIP=9 for kz=5 (halo 13/9=1.44, 882 blocks exact; STRIP does
//   not change register cost). Rows loaded as float4(+float2) — dwordx4 only
//   needs dword alignment, so 8B-aligned is fine.

template<int KZ, int W, int STRIP>
__device__ __forceinline__ float patch_strip_acc(const float* __restrict__ flow,
                                                 int nitems, int bid, int nblocks) {
    constexpr int VX     = 2;
    constexpr int Wout   = W - KZ + 1;
    constexpr int XB     = Wout / VX;       // thread-column groups
    constexpr int NSTRIP = Wout / STRIP;    // exact by construction
    constexpr int ROWS   = STRIP + KZ - 1;  // input rows touched per strip
    constexpr int NF     = VX + KZ - 1;     // floats needed per row (4 or 6)
    const float m = (KZ - 1) * 0.5f;

    float Ssum = 0.f;
#pragma unroll
    for (int t = 0; t < KZ; ++t) Ssum += (t - m) * (t - m);
    const float invS  = 1.0f / (Ssum * KZ);
    const float invk2 = 1.0f / (KZ * KZ);

    float acc = 0.f;
    for (int item = bid * blockDim.x + threadIdx.x; item < nitems;
         item += nblocks * blockDim.x) {
        // item -> (xb fastest for coalescing, strip, bc); divisors constexpr
        int xb = item % XB;
        int t1 = item / XB;
        int ys = (t1 % NSTRIP) * STRIP;
        int bc = t1 / NSTRIP;               // b*2 + channel
        const float* base = flow + (size_t)bc * (W * W) + (size_t)ys * W + xb * VX;

        float rsb[KZ][VX];   // rolling row sums
        float rssb[KZ][VX];  // rolling row sum-of-squares
        float rscb[KZ][VX];  // rolling row c-moments
#pragma unroll
        for (int r = 0; r < ROWS; ++r) {
            const float* rowp = base + r * W;
            float v[NF];
            {
                // 8B-aligned dwordx4 is legal (needs only dword alignment)
                float4 u = *reinterpret_cast<const float4*>(rowp);
                v[0] = u.x; v[1] = u.y; v[2] = u.z; v[3] = u.w;
            }
            if constexpr (NF == 6) {
                float2 u = *reinterpret_cast<const float2*>(rowp + 4);
                v[4] = u.x; v[5] = u.y;
            }
            const int slot = r % KZ;        // compile-time after full unroll
#pragma unroll
            for (int j = 0; j < VX; ++j) {
                float rs = 0.f, rss = 0.f, rsc = 0.f;
#pragma unroll
                for (int c = 0; c < KZ; ++c) {
                    float p = v[j + c];
                    rs  += p;
                    rss += p * p;
                    rsc += (c - m) * p;
                }
                rsb[slot][j]  = rs;
                rssb[slot][j] = rss;
                rscb[slot][j] = rsc;
            }
            if (r >= KZ - 1) {              // constant per unrolled iteration
                const int y = r - (KZ - 1);
#pragma unroll
                for (int j = 0; j < VX; ++j) {
                    float sum = 0.f, sumsq = 0.f, sa = 0.f, sc = 0.f;
#pragma unroll
                    for (int a = 0; a < KZ; ++a) {
                        const int s = (y + a) % KZ;   // compile-time
                        sum   += rsb[s][j];
                        sumsq += rssb[s][j];
                        sa    += (a - m) * rsb[s][j];
                        sc    += rscb[s][j];
                    }
                    acc += sumsq - sum * sum * invk2 - (sa * sa + sc * sc) * invS;
                }
            }
        }
    }
    return acc;
}

__global__ __launch_bounds__(256, 6) void fused_patch_loss(
        const float* __restrict__ flow0, const float* __restrict__ flow1,
        int nb0, int ni0, int ni1, float s0, float s1,
        float* __restrict__ partial) {
    float acc;
    if ((int)blockIdx.x < nb0) {
        acc = s0 * patch_strip_acc<3, 128, 7>(flow0, ni0, blockIdx.x, nb0);
    } else {
        acc = s1 * patch_strip_acc<5, 256, 9>(flow1, ni1, blockIdx.x - nb0,
                                              gridDim.x - nb0);
    }
    // block reduction: 64-lane shuffle then LDS across 4 waves
    for (int off = 32; off > 0; off >>= 1) acc += __shfl_down(acc, off);
    __shared__ float red[4];
    int lane = threadIdx.x & 63;
    int wid  = threadIdx.x >> 6;
    if (lane == 0) red[wid] = acc;
    __syncthreads();
    if (threadIdx.x == 0)
        partial[blockIdx.x] = red[0] + red[1] + red[2] + red[3];
}

__global__ void final_reduce_kernel(const float* __restrict__ partial, int n,
                                    float* __restrict__ out) {
    float acc = 0.f;
    for (int i = threadIdx.x; i < n; i += blockDim.x) acc += partial[i];
    for (int off = 32; off > 0; off >>= 1) acc += __shfl_down(acc, off);
    __shared__ float red[4];
    int lane = threadIdx.x & 63;
    int wid  = threadIdx.x >> 6;
    if (lane == 0) red[wid] = acc;
    __syncthreads();
    if (threadIdx.x == 0) out[0] = red[0] + red[1] + red[2] + red[3];
}

extern "C" void kernel_launch(void* const* d_in, const int* in_sizes, int n_in,
                              void* d_out, int out_size, void* d_ws, size_t ws_size,
                              hipStream_t stream) {
    const float* flow0 = (const float*)d_in[0];   // (32, 2, 128, 128)
    const float* flow1 = (const float*)d_in[1];   // (32, 2, 256, 256)
    float* out = (float*)d_out;
    float* partial = (float*)d_ws;

    // flow0: kz=3, W=128, Wout=126, VX=2, STRIP=7:
    //   items = (126/2) * (126/7) * 64 = 72,576 -> 284 blocks (ceil)
    // flow1: kz=5, W=256, Wout=252, VX=2, STRIP=9:
    //   items = (126)   * (252/9) * 64 = 225,792 -> 882 blocks (exact)
    const int ni0 = 63 * 18 * 64;
    const int ni1 = 126 * 28 * 64;
    const int nb0 = (ni0 + 255) / 256;            // 284
    const int nb1 = ni1 / 256;                    // 882
    const int nbt = nb0 + nb1;                    // 1166

    const float s0 = 1.0f / (32.0f * 126.0f * 126.0f);
    const float s1 = 1.0f / (32.0f * 252.0f * 252.0f);

    fused_patch_loss<<<nbt, 256, 0, stream>>>(flow0, flow1, nb0, ni0, ni1,
                                              s0, s1, partial);
    final_reduce_kernel<<<1, 256, 0, stream>>>(partial, nbt, out);
}

// Round 4
// 86.409 us; speedup vs baseline: 1.0782x; 1.0782x over previous
//
#include <hip/hip_runtime.h>

// loss = sum over flows/channels of mean_{b,h,w} || (I - P_A) patch ||^2
// P_A projects onto affine functions of patch offsets (a, c); the coordinate
// grids added in the reference are affine in (a,c) -> annihilated, so we can
// work on the raw flow channels.
// Residual via orthonormal basis: r = sumsq - sum^2/kz^2 - (sa^2 + sc^2)/S,
//   sa = sum (a-m) p, sc = sum (c-m) p, m = (kz-1)/2, S = kz * sum_t (t-m)^2.
//
// v5 = round-1 kernel (best measured: 76.0 us) + single-kernel reduction.
//   - VX=2, STRIP=7 both paths, float2 loads, no min-waves clause (r3's
//     launch_bounds(256,6) regressed ~10 us: VGPR cap -> spills).
//   - final_reduce kernel replaced by memset(out,0) + one device-scope
//     atomicAdd per block (removes a launch node + partial[] round-trip).

template<int KZ, int W, int STRIP>
__device__ __forceinline__ float patch_strip_acc(const float* __restrict__ flow,
                                                 int nitems, int bid, int nblocks) {
    constexpr int VX     = 2;
    constexpr int Wout   = W - KZ + 1;
    constexpr int XB     = Wout / VX;       // thread-column groups
    constexpr int NSTRIP = Wout / STRIP;    // exact: 126/7=18, 252/7=36
    constexpr int ROWS   = STRIP + KZ - 1;  // input rows touched per strip
    const float m = (KZ - 1) * 0.5f;

    float Ssum = 0.f;
#pragma unroll
    for (int t = 0; t < KZ; ++t) Ssum += (t - m) * (t - m);
    const float invS  = 1.0f / (Ssum * KZ);
    const float invk2 = 1.0f / (KZ * KZ);

    float acc = 0.f;
    for (int item = bid * blockDim.x + threadIdx.x; item < nitems;
         item += nblocks * blockDim.x) {
        // item -> (xb fastest for coalescing, strip, bc); divisors constexpr
        int xb = item % XB;
        int t1 = item / XB;
        int ys = (t1 % NSTRIP) * STRIP;
        int bc = t1 / NSTRIP;               // b*2 + channel
        const float* base = flow + (size_t)bc * (W * W) + (size_t)ys * W + xb * VX;

        float rsb[KZ][VX];   // rolling row sums
        float rssb[KZ][VX];  // rolling row sum-of-squares
        float rscb[KZ][VX];  // rolling row c-moments
#pragma unroll
        for (int r = 0; r < ROWS; ++r) {
            const float* rowp = base + r * W;
            float v[KZ + 1];
#pragma unroll
            for (int q = 0; q < (KZ + 1) / 2; ++q) {
                float2 u = *reinterpret_cast<const float2*>(rowp + 2 * q);
                v[2 * q]     = u.x;
                v[2 * q + 1] = u.y;
            }
            const int slot = r % KZ;        // compile-time after full unroll
#pragma unroll
            for (int j = 0; j < VX; ++j) {
                float rs = 0.f, rss = 0.f, rsc = 0.f;
#pragma unroll
                for (int c = 0; c < KZ; ++c) {
                    float p = v[j + c];
                    rs  += p;
                    rss += p * p;
                    rsc += (c - m) * p;
                }
                rsb[slot][j]  = rs;
                rssb[slot][j] = rss;
                rscb[slot][j] = rsc;
            }
            if (r >= KZ - 1) {              // constant per unrolled iteration
                const int y = r - (KZ - 1);
#pragma unroll
                for (int j = 0; j < VX; ++j) {
                    float sum = 0.f, sumsq = 0.f, sa = 0.f, sc = 0.f;
#pragma unroll
                    for (int a = 0; a < KZ; ++a) {
                        const int s = (y + a) % KZ;   // compile-time
                        sum   += rsb[s][j];
                        sumsq += rssb[s][j];
                        sa    += (a - m) * rsb[s][j];
                        sc    += rscb[s][j];
                    }
                    acc += sumsq - sum * sum * invk2 - (sa * sa + sc * sc) * invS;
                }
            }
        }
    }
    return acc;
}

__global__ __launch_bounds__(256) void fused_patch_loss(
        const float* __restrict__ flow0, const float* __restrict__ flow1,
        int nb0, int ni0, int ni1, float s0, float s1,
        float* __restrict__ out) {
    float acc;
    if ((int)blockIdx.x < nb0) {
        acc = s0 * patch_strip_acc<3, 128, 7>(flow0, ni0, blockIdx.x, nb0);
    } else {
        acc = s1 * patch_strip_acc<5, 256, 7>(flow1, ni1, blockIdx.x - nb0,
                                              gridDim.x - nb0);
    }
    // block reduction: 64-lane shuffle then LDS across 4 waves
    for (int off = 32; off > 0; off >>= 1) acc += __shfl_down(acc, off);
    __shared__ float red[4];
    int lane = threadIdx.x & 63;
    int wid  = threadIdx.x >> 6;
    if (lane == 0) red[wid] = acc;
    __syncthreads();
    if (threadIdx.x == 0)
        atomicAdd(out, red[0] + red[1] + red[2] + red[3]);  // device-scope
}

extern "C" void kernel_launch(void* const* d_in, const int* in_sizes, int n_in,
                              void* d_out, int out_size, void* d_ws, size_t ws_size,
                              hipStream_t stream) {
    const float* flow0 = (const float*)d_in[0];   // (32, 2, 128, 128)
    const float* flow1 = (const float*)d_in[1];   // (32, 2, 256, 256)
    float* out = (float*)d_out;

    // flow0: kz=3, W=128, Wout=126: items = (126/2) * (126/7) * 64 = 72,576
    // flow1: kz=5, W=256, Wout=252: items = (252/2) * (252/7) * 64 = 290,304
    const int ni0 = 63 * 18 * 64;
    const int ni1 = 126 * 36 * 64;
    const int nb0 = (ni0 + 255) / 256;            // 284
    const int nb1 = ni1 / 256;                    // 1134 (exact)
    const int nbt = nb0 + nb1;                    // 1418

    const float s0 = 1.0f / (32.0f * 126.0f * 126.0f);
    const float s1 = 1.0f / (32.0f * 252.0f * 252.0f);

    hipMemsetAsync(out, 0, sizeof(float), stream);
    fused_patch_loss<<<nbt, 256, 0, stream>>>(flow0, flow1, nb0, ni0, ni1,
                                              s0, s1, out);
}

// Round 6
// 76.473 us; speedup vs baseline: 1.2183x; 1.1299x over previous
//
#include <hip/hip_runtime.h>

// loss = sum over flows/channels of mean_{b,h,w} || (I - P_A) patch ||^2
// P_A projects onto affine functions of patch offsets (a, c); the coordinate
// grids added in the reference are affine in (a,c) -> annihilated, so we can
// work on the raw flow channels.
// Residual via orthonormal basis: r = sumsq - sum^2/kz^2 - (sa^2 + sc^2)/S,
//   sa = sum (a-m) p, sc = sum (c-m) p, m = (kz-1)/2, S = kz * sum_t (t-m)^2.
//
// v6 (resubmit — round-5 container failed, no data) = round-1 kernel (best
//   measured: 76.0 us) + ONE change: bijective chunked XCD swizzle (T1/m204)
//   per region. Vertically-adjacent strips sit in adjacent logical blocks;
//   default dispatch round-robins them onto different XCDs so the 4-row halo
//   (1.57x) re-fetches from HBM. Chunked mapping gives each XCD a contiguous
//   logical range -> halo becomes L2-hit.
//   r4 lesson: single-address atomicAdd burst from 1418 blocks costs ~10us —
//   two-kernel reduce restored.

__device__ __forceinline__ int xcd_chunk_map(int d, int nwg) {
    // Bijective: local dispatch residue class (= one fixed XCD) gets a
    // contiguous chunk of logical block indices. q/r split handles nwg%8 != 0.
    int q = nwg >> 3, r = nwg & 7;
    int x = d & 7, i = d >> 3;
    return (x < r) ? (x * (q + 1) + i) : (r * (q + 1) + (x - r) * q + i);
}

template<int KZ, int W, int STRIP>
__device__ __forceinline__ float patch_strip_acc(const float* __restrict__ flow,
                                                 int nitems, int bid, int nblocks) {
    constexpr int VX     = 2;
    constexpr int Wout   = W - KZ + 1;
    constexpr int XB     = Wout / VX;       // thread-column groups
    constexpr int NSTRIP = Wout / STRIP;    // exact: 126/7=18, 252/7=36
    constexpr int ROWS   = STRIP + KZ - 1;  // input rows touched per strip
    const float m = (KZ - 1) * 0.5f;

    float Ssum = 0.f;
#pragma unroll
    for (int t = 0; t < KZ; ++t) Ssum += (t - m) * (t - m);
    const float invS  = 1.0f / (Ssum * KZ);
    const float invk2 = 1.0f / (KZ * KZ);

    float acc = 0.f;
    for (int item = bid * blockDim.x + threadIdx.x; item < nitems;
         item += nblocks * blockDim.x) {
        // item -> (xb fastest for coalescing, strip, bc); divisors constexpr
        int xb = item % XB;
        int t1 = item / XB;
        int ys = (t1 % NSTRIP) * STRIP;
        int bc = t1 / NSTRIP;               // b*2 + channel
        const float* base = flow + (size_t)bc * (W * W) + (size_t)ys * W + xb * VX;

        float rsb[KZ][VX];   // rolling row sums
        float rssb[KZ][VX];  // rolling row sum-of-squares
        float rscb[KZ][VX];  // rolling row c-moments
#pragma unroll
        for (int r = 0; r < ROWS; ++r) {
            const float* rowp = base + r * W;
            float v[KZ + 1];
#pragma unroll
            for (int q = 0; q < (KZ + 1) / 2; ++q) {
                float2 u = *reinterpret_cast<const float2*>(rowp + 2 * q);
                v[2 * q]     = u.x;
                v[2 * q + 1] = u.y;
            }
            const int slot = r % KZ;        // compile-time after full unroll
#pragma unroll
            for (int j = 0; j < VX; ++j) {
                float rs = 0.f, rss = 0.f, rsc = 0.f;
#pragma unroll
                for (int c = 0; c < KZ; ++c) {
                    float p = v[j + c];
                    rs  += p;
                    rss += p * p;
                    rsc += (c - m) * p;
                }
                rsb[slot][j]  = rs;
                rssb[slot][j] = rss;
                rscb[slot][j] = rsc;
            }
            if (r >= KZ - 1) {              // constant per unrolled iteration
                const int y = r - (KZ - 1);
#pragma unroll
                for (int j = 0; j < VX; ++j) {
                    float sum = 0.f, sumsq = 0.f, sa = 0.f, sc = 0.f;
#pragma unroll
                    for (int a = 0; a < KZ; ++a) {
                        const int s = (y + a) % KZ;   // compile-time
                        sum   += rsb[s][j];
                        sumsq += rssb[s][j];
                        sa    += (a - m) * rsb[s][j];
                        sc    += rscb[s][j];
                    }
                    acc += sumsq - sum * sum * invk2 - (sa * sa + sc * sc) * invS;
                }
            }
        }
    }
    return acc;
}

__global__ __launch_bounds__(256) void fused_patch_loss(
        const float* __restrict__ flow0, const float* __restrict__ flow1,
        int nb0, int ni0, int ni1, float s0, float s1,
        float* __restrict__ partial) {
    float acc;
    if ((int)blockIdx.x < nb0) {
        int lb = xcd_chunk_map(blockIdx.x, nb0);
        acc = s0 * patch_strip_acc<3, 128, 7>(flow0, ni0, lb, nb0);
    } else {
        int nb1 = gridDim.x - nb0;
        int lb  = xcd_chunk_map(blockIdx.x - nb0, nb1);
        acc = s1 * patch_strip_acc<5, 256, 7>(flow1, ni1, lb, nb1);
    }
    // block reduction: 64-lane shuffle then LDS across 4 waves
    for (int off = 32; off > 0; off >>= 1) acc += __shfl_down(acc, off);
    __shared__ float red[4];
    int lane = threadIdx.x & 63;
    int wid  = threadIdx.x >> 6;
    if (lane == 0) red[wid] = acc;
    __syncthreads();
    if (threadIdx.x == 0)
        partial[blockIdx.x] = red[0] + red[1] + red[2] + red[3];
}

__global__ void final_reduce_kernel(const float* __restrict__ partial, int n,
                                    float* __restrict__ out) {
    float acc = 0.f;
    for (int i = threadIdx.x; i < n; i += blockDim.x) acc += partial[i];
    for (int off = 32; off > 0; off >>= 1) acc += __shfl_down(acc, off);
    __shared__ float red[4];
    int lane = threadIdx.x & 63;
    int wid  = threadIdx.x >> 6;
    if (lane == 0) red[wid] = acc;
    __syncthreads();
    if (threadIdx.x == 0) out[0] = red[0] + red[1] + red[2] + red[3];
}

extern "C" void kernel_launch(void* const* d_in, const int* in_sizes, int n_in,
                              void* d_out, int out_size, void* d_ws, size_t ws_size,
                              hipStream_t stream) {
    const float* flow0 = (const float*)d_in[0];   // (32, 2, 128, 128)
    const float* flow1 = (const float*)d_in[1];   // (32, 2, 256, 256)
    float* out = (float*)d_out;
    float* partial = (float*)d_ws;

    // flow0: kz=3, W=128, Wout=126: items = (126/2) * (126/7) * 64 = 72,576
    // flow1: kz=5, W=256, Wout=252: items = (252/2) * (252/7) * 64 = 290,304
    const int ni0 = 63 * 18 * 64;
    const int ni1 = 126 * 36 * 64;
    const int nb0 = (ni0 + 255) / 256;            // 284
    const int nb1 = ni1 / 256;                    // 1134 (exact)
    const int nbt = nb0 + nb1;                    // 1418

    const float s0 = 1.0f / (32.0f * 126.0f * 126.0f);
    const float s1 = 1.0f / (32.0f * 252.0f * 252.0f);

    fused_patch_loss<<<nbt, 256, 0, stream>>>(flow0, flow1, nb0, ni0, ni1,
                                              s0, s1, partial);
    final_reduce_kernel<<<1, 256, 0, stream>>>(partial, nbt, out);
}